// Round 1
// baseline (652.297 us; speedup 1.0000x reference)
//
#include <hip/hip_runtime.h>
#include <hip/hip_bf16.h>

// Problem dims (fixed by setup_inputs): x[8192,4096] f32, weight[4096,4096] f32,
// w_scale[32,32] f32. Output y = x @ (weight * blockscale)^T, f32 [8192,4096].
#define M_DIM 8192
#define K_DIM 4096
#define O_DIM 4096
#define QB    128

typedef __attribute__((ext_vector_type(8))) short  short8;   // 8 bf16 bits = 4 VGPRs
typedef __attribute__((ext_vector_type(4))) float  floatx4;  // MFMA accumulator

// fp32 -> bf16 bits, round-to-nearest-even
__device__ __forceinline__ short f2bf(float f) {
    unsigned u = __float_as_uint(f);
    unsigned r = u + 0x7fffu + ((u >> 16) & 1u);
    return (short)(r >> 16);
}

// ---- pre-pass 1: x (f32) -> bf16 bits, 8 elems/thread ----
__global__ __launch_bounds__(256) void cvt_x_kernel(const float* __restrict__ x,
                                                    short* __restrict__ y) {
    size_t t = (size_t)blockIdx.x * 256 + threadIdx.x;
    size_t i = t * 8;
    float4 f0 = *(const float4*)(x + i);
    float4 f1 = *(const float4*)(x + i + 4);
    short8 o;
    o[0] = f2bf(f0.x); o[1] = f2bf(f0.y); o[2] = f2bf(f0.z); o[3] = f2bf(f0.w);
    o[4] = f2bf(f1.x); o[5] = f2bf(f1.y); o[6] = f2bf(f1.z); o[7] = f2bf(f1.w);
    *(short8*)(y + i) = o;
}

// ---- pre-pass 2: weight * blockwise scale -> bf16 bits, 8 elems/thread ----
// 8 consecutive k always lie in one 128-block, so one scale per thread.
__global__ __launch_bounds__(256) void cvt_w_kernel(const float* __restrict__ w,
                                                    const float* __restrict__ s,
                                                    short* __restrict__ y) {
    size_t t = (size_t)blockIdx.x * 256 + threadIdx.x;
    size_t i = t * 8;
    int o = (int)(i >> 12);            // / K_DIM
    int k = (int)(i & (K_DIM - 1));
    float sc = s[(o >> 7) * (K_DIM / QB) + (k >> 7)];
    float4 f0 = *(const float4*)(w + i);
    float4 f1 = *(const float4*)(w + i + 4);
    short8 v;
    v[0] = f2bf(f0.x * sc); v[1] = f2bf(f0.y * sc);
    v[2] = f2bf(f0.z * sc); v[3] = f2bf(f0.w * sc);
    v[4] = f2bf(f1.x * sc); v[5] = f2bf(f1.y * sc);
    v[6] = f2bf(f1.z * sc); v[7] = f2bf(f1.w * sc);
    *(short8*)(y + i) = v;
}

// ---- m97-structure bf16 NT GEMM: C[M,O] = A[M,K] @ B[O,K]^T ----
// 128x128 tile / block, BK=32, 256 threads = 4 waves in 2x2, each wave 4x4
// subtiles of v_mfma_f32_16x16x32_bf16. Staging via global_load_lds width=16.
__global__ __launch_bounds__(256) void gemm_bt(const short* __restrict__ A,
                                               const short* __restrict__ B,
                                               float* __restrict__ C) {
    // Unpadded, lane-linear LDS: global_load_lds dest is wave-uniform base +
    // lane*16B, so layout must be exactly tid*16B contiguous.
    __shared__ __align__(16) short lsA[128 * 32];
    __shared__ __align__(16) short lsB[128 * 32];

    const int tid  = threadIdx.x;
    const int lane = tid & 63;
    const int wave = tid >> 6;
    const int bm   = blockIdx.x;   // M/128
    const int bn   = blockIdx.y;   // O/128

    const int wm = (wave >> 1) << 6;   // wave quadrant origin in tile
    const int wn = (wave & 1) << 6;

    // staging: 4 threads per row (32 elems / 8 per thread), rows 0..63 + 64..127
    const int srow = tid >> 2;
    const int scol = (tid & 3) << 3;
    const short* gA = A + (size_t)(bm * 128 + srow) * K_DIM + scol;
    const short* gB = B + (size_t)(bn * 128 + srow) * K_DIM + scol;

    auto* lA0 = (__attribute__((address_space(3))) short*)&lsA[tid * 8];
    auto* lA1 = (__attribute__((address_space(3))) short*)&lsA[(tid + 256) * 8];
    auto* lB0 = (__attribute__((address_space(3))) short*)&lsB[tid * 8];
    auto* lB1 = (__attribute__((address_space(3))) short*)&lsB[(tid + 256) * 8];

    floatx4 acc[4][4];
#pragma unroll
    for (int i = 0; i < 4; ++i)
#pragma unroll
        for (int j = 0; j < 4; ++j)
            acc[i][j] = (floatx4){0.f, 0.f, 0.f, 0.f};

    // MFMA A/B fragment address: lane holds [m|n = lane&15][k = (lane>>4)*8 + 0..7]
    const int frow = lane & 15;
    const int fcol = (lane >> 4) << 3;

    for (int k0 = 0; k0 < K_DIM; k0 += 32) {
        __syncthreads();   // prior iter's LDS reads done before overwrite
        __builtin_amdgcn_global_load_lds(
            (const __attribute__((address_space(1))) void*)gA,
            (__attribute__((address_space(3))) void*)lA0, 16, 0, 0);
        __builtin_amdgcn_global_load_lds(
            (const __attribute__((address_space(1))) void*)(gA + (size_t)64 * K_DIM),
            (__attribute__((address_space(3))) void*)lA1, 16, 0, 0);
        __builtin_amdgcn_global_load_lds(
            (const __attribute__((address_space(1))) void*)gB,
            (__attribute__((address_space(3))) void*)lB0, 16, 0, 0);
        __builtin_amdgcn_global_load_lds(
            (const __attribute__((address_space(1))) void*)(gB + (size_t)64 * K_DIM),
            (__attribute__((address_space(3))) void*)lB1, 16, 0, 0);
        gA += 32;
        gB += 32;
        __syncthreads();   // compiler emits s_waitcnt vmcnt(0) before s_barrier

        short8 av[4], bv[4];
#pragma unroll
        for (int i = 0; i < 4; ++i)
            av[i] = *(const short8*)&lsA[(wm + i * 16 + frow) * 32 + fcol];
#pragma unroll
        for (int j = 0; j < 4; ++j)
            bv[j] = *(const short8*)&lsB[(wn + j * 16 + frow) * 32 + fcol];
#pragma unroll
        for (int i = 0; i < 4; ++i)
#pragma unroll
            for (int j = 0; j < 4; ++j)
                acc[i][j] = __builtin_amdgcn_mfma_f32_16x16x32_bf16(
                    av[i], bv[j], acc[i][j], 0, 0, 0);
    }

    // Epilogue. C/D layout: col = lane&15, row = (lane>>4)*4 + reg
    const int quad  = lane >> 4;
    const int crow0 = bm * 128 + wm + quad * 4;
    const int ccol0 = bn * 128 + wn + (lane & 15);
#pragma unroll
    for (int i = 0; i < 4; ++i)
#pragma unroll
        for (int j = 0; j < 4; ++j) {
            float* cp = C + (size_t)(crow0 + i * 16) * O_DIM + (ccol0 + j * 16);
#pragma unroll
            for (int r = 0; r < 4; ++r)
                cp[(size_t)r * O_DIM] = acc[i][j][r];
        }
}

extern "C" void kernel_launch(void* const* d_in, const int* in_sizes, int n_in,
                              void* d_out, int out_size, void* d_ws, size_t ws_size,
                              hipStream_t stream) {
    const float* x  = (const float*)d_in[0];
    const float* w  = (const float*)d_in[1];
    const float* ws = (const float*)d_in[2];
    float* out = (float*)d_out;

    // workspace: [0, 64MiB) x as bf16 bits; [64MiB, 96MiB) dequant weight bf16 bits
    short* xb = (short*)d_ws;
    short* wb = xb + (size_t)M_DIM * K_DIM;

    cvt_x_kernel<<<(M_DIM * (size_t)K_DIM) / 8 / 256, 256, 0, stream>>>(x, xb);
    cvt_w_kernel<<<(O_DIM * (size_t)K_DIM) / 8 / 256, 256, 0, stream>>>(w, ws, wb);

    dim3 grid(M_DIM / 128, O_DIM / 128);
    gemm_bt<<<grid, 256, 0, stream>>>(xb, wb, out);
}

// Round 2
// 623.704 us; speedup vs baseline: 1.0458x; 1.0458x over previous
//
#include <hip/hip_runtime.h>
#include <hip/hip_bf16.h>

// y = x @ (weight * blockscale)^T ; x[8192,4096] f32, weight[4096,4096] f32,
// w_scale[32,32] f32, out f32 [8192,4096].
#define M_DIM 8192
#define K_DIM 4096
#define O_DIM 4096
#define QB    128

typedef __attribute__((ext_vector_type(8))) short  short8;   // 8 bf16 = 4 VGPRs
typedef __attribute__((ext_vector_type(4))) float  floatx4;  // MFMA accumulator

// fp32 -> bf16 bits, round-to-nearest-even
__device__ __forceinline__ short f2bf(float f) {
    unsigned u = __float_as_uint(f);
    unsigned r = u + 0x7fffu + ((u >> 16) & 1u);
    return (short)(r >> 16);
}

// ---- fused pre-pass: x -> bf16, weight*scale -> bf16, one dispatch ----
__global__ __launch_bounds__(256) void cvt_fused(const float* __restrict__ x,
                                                 const float* __restrict__ w,
                                                 const float* __restrict__ s,
                                                 short* __restrict__ xb,
                                                 short* __restrict__ wb) {
    const size_t NX = (size_t)M_DIM * K_DIM / 8;   // x threads
    size_t t = (size_t)blockIdx.x * 256 + threadIdx.x;
    if (t < NX) {
        size_t i = t * 8;
        float4 f0 = *(const float4*)(x + i);
        float4 f1 = *(const float4*)(x + i + 4);
        short8 o;
        o[0] = f2bf(f0.x); o[1] = f2bf(f0.y); o[2] = f2bf(f0.z); o[3] = f2bf(f0.w);
        o[4] = f2bf(f1.x); o[5] = f2bf(f1.y); o[6] = f2bf(f1.z); o[7] = f2bf(f1.w);
        *(short8*)(xb + i) = o;
    } else {
        size_t i = (t - NX) * 8;
        int o = (int)(i >> 12);            // / K_DIM
        int k = (int)(i & (K_DIM - 1));
        float sc = s[(o >> 7) * (K_DIM / QB) + (k >> 7)];
        float4 f0 = *(const float4*)(w + i);
        float4 f1 = *(const float4*)(w + i + 4);
        short8 v;
        v[0] = f2bf(f0.x * sc); v[1] = f2bf(f0.y * sc);
        v[2] = f2bf(f0.z * sc); v[3] = f2bf(f0.w * sc);
        v[4] = f2bf(f1.x * sc); v[5] = f2bf(f1.y * sc);
        v[6] = f2bf(f1.z * sc); v[7] = f2bf(f1.w * sc);
        *(short8*)(wb + i) = v;
    }
}

// ---- bf16 NT GEMM, m97 structure + LDS XOR swizzle + XCD-aware block map ----
// LDS row = 32 shorts (64 B) = 4 chunks of 16 B. Physical chunk p of logical
// chunk c in row r: p = c ^ ((r>>1)&3). Frag reads (16 rows, fixed c) then
// spread over all 32 banks at 2 dwords/bank (2-way = free). global_load_lds
// dest stays lane-linear; the *global* k-offset is swizzled instead.
__global__ __launch_bounds__(256) void gemm_bt(const short* __restrict__ A,
                                               const short* __restrict__ B,
                                               float* __restrict__ C) {
    __shared__ __align__(16) short lsA[128 * 32];
    __shared__ __align__(16) short lsB[128 * 32];

    const int tid  = threadIdx.x;
    const int lane = tid & 63;
    const int wave = tid >> 6;

    // XCD-aware remap (blocks round-robin over 8 XCDs by linear id):
    // XCD x owns bn in [4x, 4x+4); within it, bm sweeps with bn inner.
    // => B working set/XCD = 4 tiles (4 MB, L2-resident), A tile reused x4.
    const int id = blockIdx.x;
    const int xcd = id & 7;
    const int j   = id >> 3;          // 0..255
    const int bm  = j >> 2;           // 0..63
    const int bn  = (xcd << 2) | (j & 3);  // 0..31

    const int wm = (wave >> 1) << 6;
    const int wn = (wave & 1) << 6;

    // staging: row sr = tid>>2, physical chunk = tid&3 -> load swizzled k
    const int sr = tid >> 2;
    const int sc = (((tid & 3) ^ ((sr >> 1) & 3)) << 3);
    const short* gA = A + (size_t)(bm * 128 + sr) * K_DIM + sc;
    const short* gB = B + (size_t)(bn * 128 + sr) * K_DIM + sc;
    // rows +64: ((sr+64)>>1)&3 == (sr>>1)&3, so same sc applies.

    auto* lA0 = (__attribute__((address_space(3))) short*)&lsA[tid * 8];
    auto* lA1 = (__attribute__((address_space(3))) short*)&lsA[(tid + 256) * 8];
    auto* lB0 = (__attribute__((address_space(3))) short*)&lsB[tid * 8];
    auto* lB1 = (__attribute__((address_space(3))) short*)&lsB[(tid + 256) * 8];

    floatx4 acc[4][4];
#pragma unroll
    for (int i = 0; i < 4; ++i)
#pragma unroll
        for (int jj = 0; jj < 4; ++jj)
            acc[i][jj] = (floatx4){0.f, 0.f, 0.f, 0.f};

    // frag: row = frow (lane&15), logical chunk = lane>>4
    // physical chunk = (lane>>4) ^ ((frow>>1)&3)  (wm/i*16 shift r by mult of 16,
    // so (r>>1)&3 depends only on frow)
    const int frow = lane & 15;
    const int pc   = ((lane >> 4) ^ ((frow >> 1) & 3)) << 3;

    for (int k0 = 0; k0 < K_DIM; k0 += 32) {
        __syncthreads();
        __builtin_amdgcn_global_load_lds(
            (const __attribute__((address_space(1))) void*)gA,
            (__attribute__((address_space(3))) void*)lA0, 16, 0, 0);
        __builtin_amdgcn_global_load_lds(
            (const __attribute__((address_space(1))) void*)(gA + (size_t)64 * K_DIM),
            (__attribute__((address_space(3))) void*)lA1, 16, 0, 0);
        __builtin_amdgcn_global_load_lds(
            (const __attribute__((address_space(1))) void*)gB,
            (__attribute__((address_space(3))) void*)lB0, 16, 0, 0);
        __builtin_amdgcn_global_load_lds(
            (const __attribute__((address_space(1))) void*)(gB + (size_t)64 * K_DIM),
            (__attribute__((address_space(3))) void*)lB1, 16, 0, 0);
        gA += 32;
        gB += 32;
        __syncthreads();

        short8 av[4], bv[4];
#pragma unroll
        for (int i = 0; i < 4; ++i)
            av[i] = *(const short8*)&lsA[(wm + i * 16 + frow) * 32 + pc];
#pragma unroll
        for (int jj = 0; jj < 4; ++jj)
            bv[jj] = *(const short8*)&lsB[(wn + jj * 16 + frow) * 32 + pc];
#pragma unroll
        for (int i = 0; i < 4; ++i)
#pragma unroll
            for (int jj = 0; jj < 4; ++jj)
                acc[i][jj] = __builtin_amdgcn_mfma_f32_16x16x32_bf16(
                    av[i], bv[jj], acc[i][jj], 0, 0, 0);
    }

    // Epilogue. C/D layout: col = lane&15, row = (lane>>4)*4 + reg.
    // Nontemporal: 128 MB of C has no reuse, keep it out of L2.
    const int quad  = lane >> 4;
    const int crow0 = bm * 128 + wm + quad * 4;
    const int ccol0 = bn * 128 + wn + (lane & 15);
#pragma unroll
    for (int i = 0; i < 4; ++i)
#pragma unroll
        for (int jj = 0; jj < 4; ++jj) {
            float* cp = C + (size_t)(crow0 + i * 16) * O_DIM + (ccol0 + jj * 16);
#pragma unroll
            for (int r = 0; r < 4; ++r)
                __builtin_nontemporal_store(acc[i][jj][r], cp + (size_t)r * O_DIM);
        }
}

extern "C" void kernel_launch(void* const* d_in, const int* in_sizes, int n_in,
                              void* d_out, int out_size, void* d_ws, size_t ws_size,
                              hipStream_t stream) {
    const float* x  = (const float*)d_in[0];
    const float* w  = (const float*)d_in[1];
    const float* ws = (const float*)d_in[2];
    float* out = (float*)d_out;

    short* xb = (short*)d_ws;                       // 64 MiB bf16 x
    short* wb = xb + (size_t)M_DIM * K_DIM;         // 32 MiB bf16 dequant w

    const size_t total_t = ((size_t)M_DIM * K_DIM + (size_t)O_DIM * K_DIM) / 8;
    cvt_fused<<<(unsigned)(total_t / 256), 256, 0, stream>>>(x, w, ws, xb, wb);

    gemm_bt<<<(M_DIM / 128) * (O_DIM / 128), 256, 0, stream>>>(xb, wb, out);
}

// Round 4
// 499.864 us; speedup vs baseline: 1.3049x; 1.2477x over previous
//
#include <hip/hip_runtime.h>
#include <hip/hip_bf16.h>

// y = x @ (weight * blockscale)^T ; x[8192,4096] f32, weight[4096,4096] f32,
// w_scale[32,32] f32, out f32 [8192,4096].
#define M_DIM 8192
#define K_DIM 4096
#define O_DIM 4096
#define QB    128
#define BK    64   // K-tile per iter (halves barrier count vs 32; 32 KB LDS)

typedef __attribute__((ext_vector_type(8))) short  short8;   // 8 bf16 = 4 VGPRs
typedef __attribute__((ext_vector_type(4))) float  floatx4;  // MFMA acc / NT loads

// fp32 -> bf16 bits, round-to-nearest-even
__device__ __forceinline__ short f2bf(float f) {
    unsigned u = __float_as_uint(f);
    unsigned r = u + 0x7fffu + ((u >> 16) & 1u);
    return (short)(r >> 16);
}

// ---- fused pre-pass: x -> bf16, weight*scale -> bf16, one dispatch ----
// NT loads: fp32 inputs are read once; keep L2/L3 for xb/wb (GEMM re-reads).
__global__ __launch_bounds__(512) void cvt_fused(const float* __restrict__ x,
                                                 const float* __restrict__ w,
                                                 const float* __restrict__ s,
                                                 short* __restrict__ xb,
                                                 short* __restrict__ wb) {
    const size_t NX = (size_t)M_DIM * K_DIM / 8;   // x threads
    size_t t = (size_t)blockIdx.x * 512 + threadIdx.x;
    if (t < NX) {
        size_t i = t * 8;
        floatx4 f0 = __builtin_nontemporal_load((const floatx4*)(x + i));
        floatx4 f1 = __builtin_nontemporal_load((const floatx4*)(x + i + 4));
        short8 o;
        o[0] = f2bf(f0[0]); o[1] = f2bf(f0[1]); o[2] = f2bf(f0[2]); o[3] = f2bf(f0[3]);
        o[4] = f2bf(f1[0]); o[5] = f2bf(f1[1]); o[6] = f2bf(f1[2]); o[7] = f2bf(f1[3]);
        *(short8*)(xb + i) = o;
    } else {
        size_t i = (t - NX) * 8;
        int o = (int)(i >> 12);            // / K_DIM
        int k = (int)(i & (K_DIM - 1));
        float sc = s[(o >> 7) * (K_DIM / QB) + (k >> 7)];
        floatx4 f0 = __builtin_nontemporal_load((const floatx4*)(w + i));
        floatx4 f1 = __builtin_nontemporal_load((const floatx4*)(w + i + 4));
        short8 v;
        v[0] = f2bf(f0[0] * sc); v[1] = f2bf(f0[1] * sc);
        v[2] = f2bf(f0[2] * sc); v[3] = f2bf(f0[3] * sc);
        v[4] = f2bf(f1[0] * sc); v[5] = f2bf(f1[1] * sc);
        v[6] = f2bf(f1[2] * sc); v[7] = f2bf(f1[3] * sc);
        *(short8*)(wb + i) = v;
    }
}

// ---- bf16 NT GEMM: 128x128 tile, BK=64, XOR-swizzled LDS, XCD block map ----
// LDS row = 64 shorts (128 B) = 8 chunks of 16 B. Physical chunk of logical
// chunk c in row r: p = c ^ (r&7). Quarter-wave frag reads (16 rows, fixed c)
// then hit each chunk exactly 2x -> 2-way bank aliasing = free (m136).
// global_load_lds dest is lane-linear (tid*16B); the global k-offset carries
// the inverse swizzle, staying within one 128B segment -> still coalesced.
__global__ __launch_bounds__(256) void gemm_bt(const short* __restrict__ A,
                                               const short* __restrict__ B,
                                               float* __restrict__ C) {
    __shared__ __align__(16) short lsA[128 * BK];
    __shared__ __align__(16) short lsB[128 * BK];

    const int tid  = threadIdx.x;
    const int lane = tid & 63;
    const int wave = tid >> 6;

    // XCD map: consecutive block ids round-robin XCDs; XCD x owns bn stripe
    // [4x,4x+4) (4 MB of B resident in its L2); A tile reused x4.
    const int id  = blockIdx.x;
    const int xcd = id & 7;
    const int j   = id >> 3;
    const int bm  = j >> 2;
    const int bn  = (xcd << 2) | (j & 3);

    const int wm = (wave >> 1) << 6;
    const int wn = (wave & 1) << 6;

    // staging: thread covers row r = tid>>3 (+32 per issue), phys chunk tid&7.
    // logical chunk c = (tid&7) ^ (r&7); (r+32)&7 == r&7 so c is issue-invariant.
    const int sr = tid >> 3;
    const int sc = (((tid & 7) ^ (sr & 7)) << 3);
    const short* gA = A + (size_t)(bm * 128 + sr) * K_DIM + sc;
    const short* gB = B + (size_t)(bn * 128 + sr) * K_DIM + sc;

    floatx4 acc[4][4];
#pragma unroll
    for (int i = 0; i < 4; ++i)
#pragma unroll
        for (int jj = 0; jj < 4; ++jj)
            acc[i][jj] = (floatx4){0.f, 0.f, 0.f, 0.f};

    const int frow = lane & 15;
    const int fsw  = frow & 7;          // row-dependent chunk swizzle
    const int fc   = lane >> 4;         // logical chunk within k-half

    for (int k0 = 0; k0 < K_DIM; k0 += BK) {
        __syncthreads();
#pragma unroll
        for (int g = 0; g < 4; ++g) {
            __builtin_amdgcn_global_load_lds(
                (const __attribute__((address_space(1))) void*)(gA + (size_t)(g * 32) * K_DIM),
                (__attribute__((address_space(3))) void*)&lsA[g * 2048 + tid * 8], 16, 0, 0);
            __builtin_amdgcn_global_load_lds(
                (const __attribute__((address_space(1))) void*)(gB + (size_t)(g * 32) * K_DIM),
                (__attribute__((address_space(3))) void*)&lsB[g * 2048 + tid * 8], 16, 0, 0);
        }
        gA += BK;
        gB += BK;
        __syncthreads();

#pragma unroll
        for (int ks = 0; ks < 2; ++ks) {
            const int pc = ((ks * 4 + fc) ^ fsw) << 3;   // physical chunk * 8 shorts
            short8 av[4], bv[4];
#pragma unroll
            for (int i = 0; i < 4; ++i)
                av[i] = *(const short8*)&lsA[(wm + i * 16 + frow) * BK + pc];
#pragma unroll
            for (int jj = 0; jj < 4; ++jj)
                bv[jj] = *(const short8*)&lsB[(wn + jj * 16 + frow) * BK + pc];
#pragma unroll
            for (int i = 0; i < 4; ++i)
#pragma unroll
                for (int jj = 0; jj < 4; ++jj)
                    acc[i][jj] = __builtin_amdgcn_mfma_f32_16x16x32_bf16(
                        av[i], bv[jj], acc[i][jj], 0, 0, 0);
        }
    }

    // Epilogue. C/D layout: col = lane&15, row = (lane>>4)*4 + reg.
    const int quad  = lane >> 4;
    const int crow0 = bm * 128 + wm + quad * 4;
    const int ccol0 = bn * 128 + wn + (lane & 15);
#pragma unroll
    for (int i = 0; i < 4; ++i)
#pragma unroll
        for (int jj = 0; jj < 4; ++jj) {
            float* cp = C + (size_t)(crow0 + i * 16) * O_DIM + (ccol0 + jj * 16);
#pragma unroll
            for (int r = 0; r < 4; ++r)
                cp[(size_t)r * O_DIM] = acc[i][jj][r];
        }
}

extern "C" void kernel_launch(void* const* d_in, const int* in_sizes, int n_in,
                              void* d_out, int out_size, void* d_ws, size_t ws_size,
                              hipStream_t stream) {
    const float* x  = (const float*)d_in[0];
    const float* w  = (const float*)d_in[1];
    const float* ws = (const float*)d_in[2];
    float* out = (float*)d_out;

    short* xb = (short*)d_ws;                       // 64 MiB bf16 x
    short* wb = xb + (size_t)M_DIM * K_DIM;         // 32 MiB bf16 dequant w

    const size_t total_t = ((size_t)M_DIM * K_DIM + (size_t)O_DIM * K_DIM) / 8;
    cvt_fused<<<(unsigned)(total_t / 512), 512, 0, stream>>>(x, w, ws, xb, wb);

    gemm_bt<<<(M_DIM / 128) * (O_DIM / 128), 256, 0, stream>>>(xb, wb, out);
}